// Round 1
// baseline (216.408 us; speedup 1.0000x reference)
//
#include <hip/hip_runtime.h>
#include <hip/hip_bf16.h>

// Combine: out[b,:] = branches[argmax(gate[b,:4])][b,:]
// B=4096 rows, D=4096 fp32 per row, N=4 branches.
// Memory-bound select-copy: one 256-thread block per row, float4 vectorized.

#define B 4096
#define D 4096

__global__ __launch_bounds__(256) void combine_kernel(
    const float* __restrict__ b0, const float* __restrict__ b1,
    const float* __restrict__ b2, const float* __restrict__ b3,
    const float* __restrict__ gate, float* __restrict__ out) {

    const int row = blockIdx.x;

    // Gate row is a contiguous float4; one vector load, L1-broadcast across block.
    float4 g = ((const float4*)gate)[row];

    // First-occurrence argmax (strict > matches jnp.argmax tie-break).
    int idx = 0;
    float best = g.x;
    if (g.y > best) { best = g.y; idx = 1; }
    if (g.z > best) { best = g.z; idx = 2; }
    if (g.w > best) { best = g.w; idx = 3; }

    // Wave-uniform branch-pointer select (no divergence: idx is uniform per block).
    const float* src = (idx == 0) ? b0 : (idx == 1) ? b1 : (idx == 2) ? b2 : b3;

    const float4* s = (const float4*)(src + (size_t)row * D);
    float4*       d = (float4*)(out + (size_t)row * D);

    // 1024 float4 per row / 256 threads = 4 iterations, fully coalesced.
    #pragma unroll
    for (int k = 0; k < 4; ++k) {
        int c = threadIdx.x + k * 256;
        d[c] = s[c];
    }
}

extern "C" void kernel_launch(void* const* d_in, const int* in_sizes, int n_in,
                              void* d_out, int out_size, void* d_ws, size_t ws_size,
                              hipStream_t stream) {
    const float* b0   = (const float*)d_in[0];
    const float* b1   = (const float*)d_in[1];
    const float* b2   = (const float*)d_in[2];
    const float* b3   = (const float*)d_in[3];
    const float* gate = (const float*)d_in[4];
    float* out = (float*)d_out;

    combine_kernel<<<B, 256, 0, stream>>>(b0, b1, b2, b3, gate, out);
}